// Round 1
// baseline (1001.625 us; speedup 1.0000x reference)
//
#include <hip/hip_runtime.h>
#include <math.h>

#define N_NODES 50000
#define N_EDGES 1250000
#define D 64
#define OUTC 256  // (L+1)*D

// Copy input h into output columns [0, 64)
__global__ __launch_bounds__(256) void copy_h_kernel(const float* __restrict__ h,
                                                     float* __restrict__ out) {
    int idx = blockIdx.x * 256 + threadIdx.x;
    if (idx >= N_NODES * D) return;
    int row = idx >> 6;
    int col = idx & (D - 1);
    out[(size_t)row * OUTC + col] = h[idx];
}

// One wave per edge, lane = feature. hin/agg point into the strided output
// matrix (row stride OUTC), at the source / destination column block.
__global__ __launch_bounds__(256) void scatter_kernel(const float* __restrict__ hin,
                                                      const float* __restrict__ ew,
                                                      const int* __restrict__ src,
                                                      const int* __restrict__ dst,
                                                      float* __restrict__ agg) {
    long long gid = (long long)blockIdx.x * 256 + threadIdx.x;
    int e = (int)(gid >> 6);
    int lane = (int)(gid & 63);
    if (e >= N_EDGES) return;
    int s = src[e];
    int d = dst[e];
    float w = ew[e];
    float v = hin[(size_t)s * OUTC + lane] * w;
    atomicAdd(&agg[(size_t)d * OUTC + lane], v);
}

// In-place dense transform on a 64-wide column block of out:
// hio[row, c] = act( sum_k hio[row, k] * W[k][c] + bias[c] )
// Safe in place: each row is staged into LDS before its 64 outputs are
// overwritten, and each row belongs to exactly one block.
__global__ __launch_bounds__(256) void gemm_kernel(float* __restrict__ hio,
                                                   const float* __restrict__ W,
                                                   const float* __restrict__ bias,
                                                   int apply_tanh) {
    __shared__ float Wlds[D][D + 1];   // +1 pad: conflict-free column reads
    __shared__ float rowbuf[4][D];
    int t = threadIdx.x;
    for (int i = t; i < D * D; i += 256) {
        Wlds[i >> 6][i & (D - 1)] = W[i];
    }
    int r = t >> 6;          // 0..3 : row within 4-row group (one wave per row)
    int c = t & (D - 1);     // 0..63: output column
    float bv = bias[c];
    int row0 = blockIdx.x * 64;
    for (int rr = 0; rr < 64; rr += 4) {
        int row = row0 + rr + r;
        __syncthreads();  // also covers W load on first iteration; guards rowbuf reuse
        rowbuf[r][c] = (row < N_NODES) ? hio[(size_t)row * OUTC + c] : 0.0f;
        __syncthreads();
        float acc = bv;
#pragma unroll
        for (int k = 0; k < D; k++) {
            acc = fmaf(rowbuf[r][k], Wlds[k][c], acc);  // rowbuf: wave broadcast
        }
        if (apply_tanh) acc = tanhf(acc);
        if (row < N_NODES) hio[(size_t)row * OUTC + c] = acc;
    }
}

extern "C" void kernel_launch(void* const* d_in, const int* in_sizes, int n_in,
                              void* d_out, int out_size, void* d_ws, size_t ws_size,
                              hipStream_t stream) {
    const float* h  = (const float*)d_in[0];
    const float* ew = (const float*)d_in[1];
    const float* Ws = (const float*)d_in[2];
    const float* bs = (const float*)d_in[3];
    const int*   src = (const int*)d_in[4];
    const int*   dst = (const int*)d_in[5];
    float* out = (float*)d_out;

    // Zero entire output: columns 64..255 serve as the scatter accumulators.
    hipMemsetAsync(out, 0, (size_t)N_NODES * OUTC * sizeof(float), stream);
    copy_h_kernel<<<(N_NODES * D + 255) / 256, 256, 0, stream>>>(h, out);

    for (int i = 0; i < 3; i++) {
        const float* hin = out + (size_t)i * D;        // results[i]
        float*       agg = out + (size_t)(i + 1) * D;  // accumulator -> results[i+1]
        long long nthreads = (long long)N_EDGES * 64;
        int blocks = (int)((nthreads + 255) / 256);
        scatter_kernel<<<blocks, 256, 0, stream>>>(hin, ew, src, dst, agg);
        gemm_kernel<<<(N_NODES + 63) / 64, 256, 0, stream>>>(
            agg, Ws + (size_t)i * D * D, bs + (size_t)i * D, (i < 2) ? 1 : 0);
    }
}

// Round 2
// 753.410 us; speedup vs baseline: 1.3295x; 1.3295x over previous
//
#include <hip/hip_runtime.h>
#include <math.h>

#define N_NODES 50000
#define N_EDGES 1250000
#define D 64
#define OUTC 256  // (L+1)*D

// ---------------- workspace layout (bytes) ----------------
// deg:     [0,       200000)   50000 ints (in-degree histogram)
// fill:    [204800,  404800)   50000 ints (fill cursors)
// row_ptr: [409600,  609604)   50001 ints (CSR row pointers)
// edges:   [614400,  614400+10MB)  1.25M int2 {src, bits(w)} sorted by dst
#define WS_DEG      0
#define WS_FILL     204800
#define WS_ROWPTR   409600
#define WS_EDGES    614400
#define WS_NEEDED   (WS_EDGES + (size_t)N_EDGES * 8)

// Copy input h into output columns [0, 64), vectorized float4.
__global__ __launch_bounds__(256) void copy_h_kernel(const float* __restrict__ h,
                                                     float* __restrict__ out) {
    int idx = blockIdx.x * 256 + threadIdx.x;  // one float4 per thread
    if (idx >= N_NODES * D / 4) return;
    int row = idx >> 4;           // 16 float4 per row
    int c4  = idx & 15;
    const float4* hv = (const float4*)h;
    float4* ov = (float4*)(out + (size_t)row * OUTC);
    ov[c4] = hv[idx];
}

// In-degree histogram.
__global__ __launch_bounds__(256) void hist_kernel(const int* __restrict__ dst,
                                                   int* __restrict__ deg) {
    int e = blockIdx.x * 256 + threadIdx.x;
    if (e >= N_EDGES) return;
    atomicAdd(&deg[dst[e]], 1);
}

// Exclusive scan of deg -> row_ptr, single block of 1024 threads,
// wave-shfl scans (2 barriers per 1024-chunk).
__global__ __launch_bounds__(1024) void scan_kernel(const int* __restrict__ deg,
                                                    int* __restrict__ row_ptr) {
    __shared__ int wsum[16];
    int t = threadIdx.x, lane = t & 63, w = t >> 6;
    int carry = 0;
    for (int base = 0; base < N_NODES; base += 1024) {
        int i = base + t;
        int v = (i < N_NODES) ? deg[i] : 0;
        int x = v;  // inclusive wave scan
#pragma unroll
        for (int off = 1; off < 64; off <<= 1) {
            int y = __shfl_up(x, off);
            if (lane >= off) x += y;
        }
        if (lane == 63) wsum[w] = x;
        __syncthreads();
        if (w == 0) {
            int s = (lane < 16) ? wsum[lane] : 0;
#pragma unroll
            for (int off = 1; off < 16; off <<= 1) {
                int y = __shfl_up(s, off);
                if (lane >= off) s += y;
            }
            if (lane < 16) wsum[lane] = s;
        }
        __syncthreads();
        int woff = (w > 0) ? wsum[w - 1] : 0;
        if (i < N_NODES) row_ptr[i] = carry + woff + (x - v);
        carry += wsum[15];  // chunk total (uniform across block)
        __syncthreads();    // protect wsum before next chunk
    }
    if (t == 0) row_ptr[N_NODES] = carry;
}

// Scatter edges into CSR buckets: edges_sorted[row_ptr[d] + cursor] = {src, w}.
__global__ __launch_bounds__(256) void fill_kernel(const int* __restrict__ src,
                                                   const int* __restrict__ dst,
                                                   const float* __restrict__ ew,
                                                   const int* __restrict__ row_ptr,
                                                   int* __restrict__ fill,
                                                   int2* __restrict__ edges) {
    int e = blockIdx.x * 256 + threadIdx.x;
    if (e >= N_EDGES) return;
    int d = dst[e];
    int p = atomicAdd(&fill[d], 1);
    edges[row_ptr[d] + p] = make_int2(src[e], __float_as_int(ew[e]));
}

// Fused per-layer kernel: one wave per node (grid-stride), lane = feature.
//   acc[lane] = sum_{e in-edges(n)} w_e * hin[src_e][lane]     (coalesced 256B gathers)
//   out[lane] = act( bias[lane] + sum_k shfl(acc,k) * Wreg[k] ) (readlane broadcast, W column in VGPRs)
#define LAYER_BLOCKS 1280
__global__ __launch_bounds__(256) void layer_kernel(const float* __restrict__ hin,
                                                    const int2* __restrict__ edges,
                                                    const int* __restrict__ row_ptr,
                                                    const float* __restrict__ W,
                                                    const float* __restrict__ bias,
                                                    float* __restrict__ hout,
                                                    int apply_tanh) {
    int t = threadIdx.x, lane = t & 63, wv = t >> 6;
    float Wreg[64];
#pragma unroll
    for (int k = 0; k < 64; k++) Wreg[k] = W[k * 64 + lane];  // W column `lane`
    float bv = bias[lane];
    int waveId = blockIdx.x * 4 + wv;
    const int nWaves = LAYER_BLOCKS * 4;
    for (int n = waveId; n < N_NODES; n += nWaves) {
        int beg = row_ptr[n], end = row_ptr[n + 1];
        float acc = 0.0f;
        int j = beg;
        for (; j + 1 < end; j += 2) {  // unroll-2 for memory-level parallelism
            int2 r0 = edges[j], r1 = edges[j + 1];
            float v0 = hin[(size_t)r0.x * OUTC + lane];
            float v1 = hin[(size_t)r1.x * OUTC + lane];
            acc = fmaf(v0, __int_as_float(r0.y), acc);
            acc = fmaf(v1, __int_as_float(r1.y), acc);
        }
        if (j < end) {
            int2 r0 = edges[j];
            acc = fmaf(hin[(size_t)r0.x * OUTC + lane], __int_as_float(r0.y), acc);
        }
        // 64x64 transform: 4 independent FMA chains to break latency.
        float o0 = bv, o1 = 0.f, o2 = 0.f, o3 = 0.f;
#pragma unroll
        for (int k = 0; k < 64; k += 4) {
            o0 = fmaf(__shfl(acc, k + 0), Wreg[k + 0], o0);
            o1 = fmaf(__shfl(acc, k + 1), Wreg[k + 1], o1);
            o2 = fmaf(__shfl(acc, k + 2), Wreg[k + 2], o2);
            o3 = fmaf(__shfl(acc, k + 3), Wreg[k + 3], o3);
        }
        float o = (o0 + o1) + (o2 + o3);
        if (apply_tanh) o = tanhf(o);
        hout[(size_t)n * OUTC + lane] = o;
    }
}

// ---------------- fallback (atomic) path, used only if ws is too small ------
__global__ __launch_bounds__(256) void scatter_kernel(const float* __restrict__ hin,
                                                      const float* __restrict__ ew,
                                                      const int* __restrict__ src,
                                                      const int* __restrict__ dst,
                                                      float* __restrict__ agg) {
    long long gid = (long long)blockIdx.x * 256 + threadIdx.x;
    int e = (int)(gid >> 6);
    int lane = (int)(gid & 63);
    if (e >= N_EDGES) return;
    float v = hin[(size_t)src[e] * OUTC + lane] * ew[e];
    atomicAdd(&agg[(size_t)dst[e] * OUTC + lane], v);
}

__global__ __launch_bounds__(256) void gemm_kernel(float* __restrict__ hio,
                                                   const float* __restrict__ W,
                                                   const float* __restrict__ bias,
                                                   int apply_tanh) {
    __shared__ float Wlds[D][D + 1];
    __shared__ float rowbuf[4][D];
    int t = threadIdx.x;
    for (int i = t; i < D * D; i += 256) Wlds[i >> 6][i & (D - 1)] = W[i];
    int r = t >> 6, c = t & (D - 1);
    float bv = bias[c];
    int row0 = blockIdx.x * 64;
    for (int rr = 0; rr < 64; rr += 4) {
        int row = row0 + rr + r;
        __syncthreads();
        rowbuf[r][c] = (row < N_NODES) ? hio[(size_t)row * OUTC + c] : 0.0f;
        __syncthreads();
        float acc = bv;
#pragma unroll
        for (int k = 0; k < D; k++) acc = fmaf(rowbuf[r][k], Wlds[k][c], acc);
        if (apply_tanh) acc = tanhf(acc);
        if (row < N_NODES) hio[(size_t)row * OUTC + c] = acc;
    }
}

extern "C" void kernel_launch(void* const* d_in, const int* in_sizes, int n_in,
                              void* d_out, int out_size, void* d_ws, size_t ws_size,
                              hipStream_t stream) {
    const float* h   = (const float*)d_in[0];
    const float* ew  = (const float*)d_in[1];
    const float* Ws  = (const float*)d_in[2];
    const float* bs  = (const float*)d_in[3];
    const int*   src = (const int*)d_in[4];
    const int*   dst = (const int*)d_in[5];
    float* out = (float*)d_out;

    if (ws_size >= WS_NEEDED) {
        char* ws = (char*)d_ws;
        int*  deg     = (int*)(ws + WS_DEG);
        int*  fill    = (int*)(ws + WS_FILL);
        int*  row_ptr = (int*)(ws + WS_ROWPTR);
        int2* edges   = (int2*)(ws + WS_EDGES);

        hipMemsetAsync(ws, 0, WS_ROWPTR, stream);  // zero deg + fill
        copy_h_kernel<<<(N_NODES * D / 4 + 255) / 256, 256, 0, stream>>>(h, out);
        hist_kernel<<<(N_EDGES + 255) / 256, 256, 0, stream>>>(dst, deg);
        scan_kernel<<<1, 1024, 0, stream>>>(deg, row_ptr);
        fill_kernel<<<(N_EDGES + 255) / 256, 256, 0, stream>>>(src, dst, ew, row_ptr, fill, edges);

        for (int i = 0; i < 3; i++) {
            const float* hin = out + (size_t)i * D;
            float*       hout = out + (size_t)(i + 1) * D;
            layer_kernel<<<LAYER_BLOCKS, 256, 0, stream>>>(
                hin, edges, row_ptr, Ws + (size_t)i * D * D, bs + (size_t)i * D,
                hout, (i < 2) ? 1 : 0);
        }
    } else {
        // Fallback: atomic scatter path (R1 implementation).
        hipMemsetAsync(out, 0, (size_t)N_NODES * OUTC * sizeof(float), stream);
        copy_h_kernel<<<(N_NODES * D / 4 + 255) / 256, 256, 0, stream>>>(h, out);
        for (int i = 0; i < 3; i++) {
            const float* hin = out + (size_t)i * D;
            float*       agg = out + (size_t)(i + 1) * D;
            long long nthreads = (long long)N_EDGES * 64;
            scatter_kernel<<<(int)((nthreads + 255) / 256), 256, 0, stream>>>(hin, ew, src, dst, agg);
            gemm_kernel<<<(N_NODES + 63) / 64, 256, 0, stream>>>(
                agg, Ws + (size_t)i * D * D, bs + (size_t)i * D, (i < 2) ? 1 : 0);
        }
    }
}

// Round 3
// 507.722 us; speedup vs baseline: 1.9728x; 1.4839x over previous
//
#include <hip/hip_runtime.h>
#include <hip/hip_fp16.h>
#include <math.h>

#define N_NODES 50000
#define N_EDGES 1250000
#define D 64
#define OUTC 256  // (L+1)*D

// ---------------- workspace layout (bytes) ----------------
#define WS_DEG      0                                    // 50000 ints
#define WS_FILL     204800                               // 50000 ints
#define WS_ROWPTR   409600                               // 50001 ints
#define WS_EDGES    614400                               // 1.25M int2 {src, bits(w)} by dst
#define WS_H16_0    10616832                             // 50000*64 half (6.4 MB), 4K-aligned
#define WS_H16_1    (WS_H16_0 + (size_t)N_NODES * D * 2)
#define WS_F16_NEEDED (WS_H16_1 + (size_t)N_NODES * D * 2)   // ~23.4 MB
#define WS_CSR_NEEDED (WS_EDGES + (size_t)N_EDGES * 8)       // ~10.6 MB

// Copy input h into output columns [0,64) and (optionally) fp16 mirror.
__global__ __launch_bounds__(256) void copy_h_kernel(const float* __restrict__ h,
                                                     float* __restrict__ out,
                                                     __half* __restrict__ h16) {
    int idx = blockIdx.x * 256 + threadIdx.x;  // one float4 per thread
    if (idx >= N_NODES * D / 4) return;
    int row = idx >> 4;
    int c4  = idx & 15;
    float4 v = ((const float4*)h)[idx];
    ((float4*)(out + (size_t)row * OUTC))[c4] = v;
    if (h16) {
        __half2* p = (__half2*)(h16 + (size_t)row * D + c4 * 4);
        p[0] = __floats2half2_rn(v.x, v.y);
        p[1] = __floats2half2_rn(v.z, v.w);
    }
}

__global__ __launch_bounds__(256) void hist_kernel(const int* __restrict__ dst,
                                                   int* __restrict__ deg) {
    int e = blockIdx.x * 256 + threadIdx.x;
    if (e >= N_EDGES) return;
    atomicAdd(&deg[dst[e]], 1);
}

// Exclusive scan deg -> row_ptr, single 1024-thread block, wave-shfl scans.
__global__ __launch_bounds__(1024) void scan_kernel(const int* __restrict__ deg,
                                                    int* __restrict__ row_ptr) {
    __shared__ int wsum[16];
    int t = threadIdx.x, lane = t & 63, w = t >> 6;
    int carry = 0;
    for (int base = 0; base < N_NODES; base += 1024) {
        int i = base + t;
        int v = (i < N_NODES) ? deg[i] : 0;
        int x = v;
#pragma unroll
        for (int off = 1; off < 64; off <<= 1) {
            int y = __shfl_up(x, off);
            if (lane >= off) x += y;
        }
        if (lane == 63) wsum[w] = x;
        __syncthreads();
        if (w == 0) {
            int s = (lane < 16) ? wsum[lane] : 0;
#pragma unroll
            for (int off = 1; off < 16; off <<= 1) {
                int y = __shfl_up(s, off);
                if (lane >= off) s += y;
            }
            if (lane < 16) wsum[lane] = s;
        }
        __syncthreads();
        int woff = (w > 0) ? wsum[w - 1] : 0;
        if (i < N_NODES) row_ptr[i] = carry + woff + (x - v);
        carry += wsum[15];
        __syncthreads();
    }
    if (t == 0) row_ptr[N_NODES] = carry;
}

__global__ __launch_bounds__(256) void fill_kernel(const int* __restrict__ src,
                                                   const int* __restrict__ dst,
                                                   const float* __restrict__ ew,
                                                   const int* __restrict__ row_ptr,
                                                   int* __restrict__ fill,
                                                   int2* __restrict__ edges) {
    int e = blockIdx.x * 256 + threadIdx.x;
    if (e >= N_EDGES) return;
    int d = dst[e];
    int p = atomicAdd(&fill[d], 1);
    edges[row_ptr[d] + p] = make_int2(src[e], __float_as_int(ew[e]));
}

// Fused layer: one wave per node (grid-stride), lane = feature.
// Edge chunk of 16 loaded coalesced + shfl-broadcast; 16 independent row
// gathers in flight before the FMA chain (MLP ~16/wave). Gather source is
// either the compact fp16 mirror (USE_F16) or strided f32 out columns.
#define LAYER_BLOCKS 3125
template <bool USE_F16>
__global__ __launch_bounds__(256) void layer_kernel(const __half* __restrict__ h16src,
                                                    const float* __restrict__ hfsrc,
                                                    const int2* __restrict__ edges,
                                                    const int* __restrict__ row_ptr,
                                                    const float* __restrict__ W,
                                                    const float* __restrict__ bias,
                                                    float* __restrict__ hout,
                                                    __half* __restrict__ h16out,
                                                    int apply_tanh) {
    __shared__ float Wlds[D * D];  // row-major; row reads are conflict-free
    int t = threadIdx.x, lane = t & 63, wv = t >> 6;
    for (int i = t; i < D * D; i += 256) Wlds[i] = W[i];
    __syncthreads();
    float bv = bias[lane];
    int waveId = blockIdx.x * 4 + wv;
    const int nWaves = LAYER_BLOCKS * 4;
    for (int n = waveId; n < N_NODES; n += nWaves) {
        int beg = row_ptr[n], end = row_ptr[n + 1];
        float acc = 0.0f;
        for (int j = beg; j < end; j += 16) {
            int rem = end - j;  // wave-uniform
            int idx = j + (lane & 15);
            if (idx >= N_EDGES) idx = N_EDGES - 1;   // tail clamp (unused lanes)
            int2 er = edges[idx];                     // lanes 0-15 pattern, 128B
            float vv[16], ww[16];
#pragma unroll
            for (int l = 0; l < 16; l++) {
                int   s  = __shfl(er.x, l);
                float wl = __int_as_float(__shfl(er.y, l));
                bool ok = (l < rem);
                int ss = ok ? s : 0;                  // harmless hot row-0 load
                ww[l] = ok ? wl : 0.0f;
                vv[l] = USE_F16 ? __half2float(h16src[(size_t)ss * D + lane])
                                : hfsrc[(size_t)ss * OUTC + lane];
            }
#pragma unroll
            for (int l = 0; l < 16; l++) acc = fmaf(vv[l], ww[l], acc);
        }
        // 64x64 transform: shfl broadcast of acc, W rows from LDS, 4 chains.
        float o0 = bv, o1 = 0.f, o2 = 0.f, o3 = 0.f;
#pragma unroll
        for (int k = 0; k < D; k += 4) {
            o0 = fmaf(__shfl(acc, k + 0), Wlds[(k + 0) * D + lane], o0);
            o1 = fmaf(__shfl(acc, k + 1), Wlds[(k + 1) * D + lane], o1);
            o2 = fmaf(__shfl(acc, k + 2), Wlds[(k + 2) * D + lane], o2);
            o3 = fmaf(__shfl(acc, k + 3), Wlds[(k + 3) * D + lane], o3);
        }
        float o = (o0 + o1) + (o2 + o3);
        if (apply_tanh) o = tanhf(o);
        hout[(size_t)n * OUTC + lane] = o;
        if (h16out) h16out[(size_t)n * D + lane] = __float2half(o);
    }
}

// ---------------- atomic fallback (tiny ws) ----------------
__global__ __launch_bounds__(256) void scatter_kernel(const float* __restrict__ hin,
                                                      const float* __restrict__ ew,
                                                      const int* __restrict__ src,
                                                      const int* __restrict__ dst,
                                                      float* __restrict__ agg) {
    long long gid = (long long)blockIdx.x * 256 + threadIdx.x;
    int e = (int)(gid >> 6);
    int lane = (int)(gid & 63);
    if (e >= N_EDGES) return;
    float v = hin[(size_t)src[e] * OUTC + lane] * ew[e];
    atomicAdd(&agg[(size_t)dst[e] * OUTC + lane], v);
}

__global__ __launch_bounds__(256) void gemm_kernel(float* __restrict__ hio,
                                                   const float* __restrict__ W,
                                                   const float* __restrict__ bias,
                                                   int apply_tanh) {
    __shared__ float Wl[D][D + 1];
    __shared__ float rowbuf[4][D];
    int t = threadIdx.x;
    for (int i = t; i < D * D; i += 256) Wl[i >> 6][i & (D - 1)] = W[i];
    int r = t >> 6, c = t & (D - 1);
    float bv = bias[c];
    int row0 = blockIdx.x * 64;
    for (int rr = 0; rr < 64; rr += 4) {
        int row = row0 + rr + r;
        __syncthreads();
        rowbuf[r][c] = (row < N_NODES) ? hio[(size_t)row * OUTC + c] : 0.0f;
        __syncthreads();
        float acc = bv;
#pragma unroll
        for (int k = 0; k < D; k++) acc = fmaf(rowbuf[r][k], Wl[k][c], acc);
        if (apply_tanh) acc = tanhf(acc);
        if (row < N_NODES) hio[(size_t)row * OUTC + c] = acc;
    }
}

extern "C" void kernel_launch(void* const* d_in, const int* in_sizes, int n_in,
                              void* d_out, int out_size, void* d_ws, size_t ws_size,
                              hipStream_t stream) {
    const float* h   = (const float*)d_in[0];
    const float* ew  = (const float*)d_in[1];
    const float* Ws  = (const float*)d_in[2];
    const float* bs  = (const float*)d_in[3];
    const int*   src = (const int*)d_in[4];
    const int*   dst = (const int*)d_in[5];
    float* out = (float*)d_out;

    if (ws_size >= WS_CSR_NEEDED) {
        char* ws = (char*)d_ws;
        int*  deg     = (int*)(ws + WS_DEG);
        int*  fill    = (int*)(ws + WS_FILL);
        int*  row_ptr = (int*)(ws + WS_ROWPTR);
        int2* edges   = (int2*)(ws + WS_EDGES);
        bool use_f16 = (ws_size >= WS_F16_NEEDED);
        __half* h16a = use_f16 ? (__half*)(ws + WS_H16_0) : nullptr;
        __half* h16b = use_f16 ? (__half*)(ws + WS_H16_1) : nullptr;

        hipMemsetAsync(ws, 0, WS_ROWPTR, stream);  // zero deg + fill
        copy_h_kernel<<<(N_NODES * D / 4 + 255) / 256, 256, 0, stream>>>(h, out, h16a);
        hist_kernel<<<(N_EDGES + 255) / 256, 256, 0, stream>>>(dst, deg);
        scan_kernel<<<1, 1024, 0, stream>>>(deg, row_ptr);
        fill_kernel<<<(N_EDGES + 255) / 256, 256, 0, stream>>>(src, dst, ew, row_ptr, fill, edges);

        for (int i = 0; i < 3; i++) {
            float* hout = out + (size_t)(i + 1) * D;
            const float* Wi = Ws + (size_t)i * D * D;
            const float* bi = bs + (size_t)i * D;
            int tanh_f = (i < 2) ? 1 : 0;
            if (use_f16) {
                __half* hsrc = (i & 1) ? h16b : h16a;
                __half* hdst = (i == 2) ? nullptr : ((i & 1) ? h16a : h16b);
                layer_kernel<true><<<LAYER_BLOCKS, 256, 0, stream>>>(
                    hsrc, nullptr, edges, row_ptr, Wi, bi, hout, hdst, tanh_f);
            } else {
                const float* hfsrc = out + (size_t)i * D;
                layer_kernel<false><<<LAYER_BLOCKS, 256, 0, stream>>>(
                    nullptr, hfsrc, edges, row_ptr, Wi, bi, hout, nullptr, tanh_f);
            }
        }
    } else {
        hipMemsetAsync(out, 0, (size_t)N_NODES * OUTC * sizeof(float), stream);
        copy_h_kernel<<<(N_NODES * D / 4 + 255) / 256, 256, 0, stream>>>(h, out, nullptr);
        for (int i = 0; i < 3; i++) {
            const float* hin = out + (size_t)i * D;
            float*       agg = out + (size_t)(i + 1) * D;
            long long nthreads = (long long)N_EDGES * 64;
            scatter_kernel<<<(int)((nthreads + 255) / 256), 256, 0, stream>>>(hin, ew, src, dst, agg);
            gemm_kernel<<<(N_NODES + 63) / 64, 256, 0, stream>>>(
                agg, Ws + (size_t)i * D * D, bs + (size_t)i * D, (i < 2) ? 1 : 0);
        }
    }
}